// Round 14
// baseline (93.644 us; speedup 1.0000x reference)
//
#include <hip/hip_runtime.h>
#include <hip/hip_bf16.h>

typedef __attribute__((ext_vector_type(8))) short short8;
typedef __attribute__((ext_vector_type(4))) float f32x4;
typedef _Float16 __attribute__((ext_vector_type(2))) half2v;

#define INV_TEMP 14.285714285714286f
#define LOGIT_MAX 14.2857143f
#define L2E 1.44269504f
#define OFFE (LOGIT_MAX * L2E)
#define PCLIP 0.23f
#define PDELTA (PCLIP / 7.f)
#define PQS (7.f / PCLIP)

#if __has_builtin(__builtin_amdgcn_sdot8)
#define HAVE_SDOT8 1
#else
#define HAVE_SDOT8 0
#endif

__device__ __forceinline__ ushort bf16c(float f) {
  uint u = __float_as_uint(f);
  uint r = (u + 0x7fffu + ((u >> 16) & 1u)) >> 16;
  return (ushort)r;
}
__device__ __forceinline__ uint pk2(float a, float b) {
  return (uint)bf16c(a) | ((uint)bf16c(b) << 16);
}
__device__ __forceinline__ uint pkh(float a, float b) {
  return __builtin_bit_cast(uint, __builtin_amdgcn_cvt_pkrtz(a, b));
}
__device__ __forceinline__ half2v h2(uint u) {
  return __builtin_bit_cast(half2v, u);
}
__device__ __forceinline__ int sdot4_(uint a, uint b, int c) {
  return __builtin_amdgcn_sdot4((int)a, (int)b, c, false);
}
#if HAVE_SDOT8
__device__ __forceinline__ int sdot8_(uint a, uint b, int c) {
  return __builtin_amdgcn_sdot8((int)a, (int)b, c, false);
}
#endif
// async global->LDS, 16B per lane; LDS dest = wave-uniform base + lane*16
__device__ __forceinline__ void gl_lds16(const void* g, void* l) {
  __builtin_amdgcn_global_load_lds(
      (const __attribute__((address_space(1))) void*)g,
      (__attribute__((address_space(3))) void*)l, 16, 0, 0);
}

template <int CTRL>
__device__ __forceinline__ float dpp_add(float v) {
  const int x = __builtin_amdgcn_mov_dpp(__float_as_int(v), CTRL, 0xF, 0xF, true);
  return v + __int_as_float(x);
}
template <int CTRL>
__device__ __forceinline__ int dpp_addi(int v) {
  return v + __builtin_amdgcn_mov_dpp(v, CTRL, 0xF, 0xF, true);
}
__device__ __forceinline__ float qsum16(float v) {
  v = dpp_add<0xB1>(v);
  v = dpp_add<0x4E>(v);
  v = dpp_add<0x141>(v);
  v = dpp_add<0x140>(v);
  return v;
}
__device__ __forceinline__ int qsum8i(int v) {
  v = dpp_addi<0xB1>(v);
  v = dpp_addi<0x4E>(v);
  v = dpp_addi<0x141>(v);
  return v;
}

// ---------- prep: cvt ctx ([0,512)), cvt W ([512,1280)), pool int4 ([1280,1408)) ----------
__global__ __launch_bounds__(256) void prep_kernel(
    const float* __restrict__ ctx, const float* __restrict__ W,
    const float* __restrict__ enc, ushort* __restrict__ ctxb,
    ushort* __restrict__ Wb, uint* __restrict__ pool4,
    float* __restrict__ acc, int* __restrict__ cnt) {
  const int bid = blockIdx.x;
  const int tid = threadIdx.x;
  if (bid < 1280) {
    const float* in;
    ushort* out;
    size_t i;
    if (bid < 512) { in = ctx; out = ctxb; i = (size_t)bid * 256 + tid; }
    else           { in = W;   out = Wb;   i = (size_t)(bid - 512) * 256 + tid; }
    const float4 a = *(const float4*)(in + i * 8);
    const float4 b = *(const float4*)(in + i * 8 + 4);
    const uint4 o = make_uint4(pk2(a.x, a.y), pk2(a.z, a.w), pk2(b.x, b.y), pk2(b.z, b.w));
    *(uint4*)(out + i * 8) = o;
    return;
  }
  // pool: p' = clamp(rint(e_norm/PDELTA),-7,7)+8, nibble n of uint j = chan 8j+n
  if (bid == 1280) {
    if (tid < 12) acc[tid] = 0.f;
    if (tid == 12) *cnt = 0;
  }
  const int grp = tid >> 4, lane = tid & 15;
  const int r = (bid - 1280) * 16 + grp;  // 0..2047
  const float* src = enc + (size_t)r * 256 + lane * 16;
  float4 v0 = *(const float4*)(src);
  float4 v1 = *(const float4*)(src + 4);
  float4 v2 = *(const float4*)(src + 8);
  float4 v3 = *(const float4*)(src + 12);
  float c[16] = {v0.x, v0.y, v0.z, v0.w, v1.x, v1.y, v1.z, v1.w,
                 v2.x, v2.y, v2.z, v2.w, v3.x, v3.y, v3.z, v3.w};
  float ss = 0.f;
#pragma unroll
  for (int i = 0; i < 16; ++i) ss = fmaf(c[i], c[i], ss);
  ss = qsum16(ss);
  const float qs = rsqrtf(ss) * PQS;
  uint w0 = 0, w1 = 0;
#pragma unroll
  for (int n = 0; n < 8; ++n) {
    const int q0 = (int)rintf(fminf(fmaxf(c[n] * qs, -7.f), 7.f)) + 8;
    const int q1 = (int)rintf(fminf(fmaxf(c[8 + n] * qs, -7.f), 7.f)) + 8;
    w0 |= (uint)q0 << (4 * n);
    w1 |= (uint)q1 << (4 * n);
  }
  *(uint2*)(pool4 + (size_t)r * 32 + lane * 2) = make_uint2(w0, w1);
}

// ---------- z_hat[k] = ctx_rows @ W[k]^T, bf16 MFMA, 2-phase double-buffered gl_lds ----------
__global__ __launch_bounds__(256) void zhat_gemm_kernel(
    const ushort* __restrict__ ctxb, const ushort* __restrict__ Wb,
    uint* __restrict__ Zp) {
  const int kk = blockIdx.z;
  const int Tk = 255 - kk, Nk = 8 * Tk;
  const int rowbase = blockIdx.y * 64;
  if (rowbase >= Nk) return;
  const int colbase = blockIdx.x * 128;

  __shared__ __attribute__((aligned(16))) ushort As[2][64 * 32];    // 2 x 4 KB
  __shared__ __attribute__((aligned(16))) ushort Bs[2][128 * 32];   // 2 x 8 KB

  const int tid = threadIdx.x;
  const int wid = tid >> 6, lane = tid & 63;
  const int arow = tid & 63;
  int n = rowbase + arow;
  if (n >= Nk) n = Nk - 1;  // clamp (valid memory; result rows discarded)
  const int bb = n / Tk, tt = n - bb * Tk;
  const ushort* aptr = ctxb + ((size_t)(bb * 256 + tt)) * 512 + (tid >> 6) * 8;
  const int brow = tid & 127;
  const ushort* bptr = Wb + ((size_t)kk * 256 + colbase + brow) * 512 + (tid >> 7) * 8;

  const int wm = wid >> 1, wn = wid & 1;
  const int l15 = lane & 15, l16 = lane >> 4;
  const int wboff = wid * 1024;

  f32x4 acc[2][4];
#pragma unroll
  for (int i = 0; i < 2; ++i)
#pragma unroll
    for (int j = 0; j < 4; ++j) acc[i][j] = (f32x4){0.f, 0.f, 0.f, 0.f};

  const size_t aoff = (size_t)(l16 * 64 + wm * 32 + l15) * 8;
  const size_t boff = (size_t)(l16 * 128 + wn * 64 + l15) * 8;

#define STAGE(B, K0)                                              \
  gl_lds16(aptr + (K0), (char*)As[B] + wboff);                    \
  gl_lds16(bptr + (K0), (char*)Bs[B] + wboff);                    \
  gl_lds16(bptr + (K0) + 16, (char*)Bs[B] + wboff + 4096);

#define SYNCPT                                                    \
  asm volatile("s_waitcnt vmcnt(0)" ::: "memory");                \
  __builtin_amdgcn_s_barrier();                                   \
  __builtin_amdgcn_sched_barrier(0);

#define COMPUTE(B)                                                              \
  {                                                                             \
    const ushort* ar = As[B] + aoff;                                            \
    const ushort* br = Bs[B] + boff;                                            \
    short8 bf[4];                                                               \
    bf[0] = *(const short8*)(br);                                               \
    bf[1] = *(const short8*)(br + 128);                                         \
    bf[2] = *(const short8*)(br + 256);                                         \
    bf[3] = *(const short8*)(br + 384);                                         \
    const short8 a0 = *(const short8*)(ar);                                     \
    const short8 a1 = *(const short8*)(ar + 128);                               \
    _Pragma("unroll")                                                           \
    for (int nb = 0; nb < 4; ++nb) {                                            \
      acc[0][nb] = __builtin_amdgcn_mfma_f32_16x16x32_bf16(a0, bf[nb], acc[0][nb], 0, 0, 0); \
      acc[1][nb] = __builtin_amdgcn_mfma_f32_16x16x32_bf16(a1, bf[nb], acc[1][nb], 0, 0, 0); \
    }                                                                           \
  }

  STAGE(0, 0)
  SYNCPT
  for (int k0 = 0; k0 < 512; k0 += 64) {
    STAGE(1, k0 + 32)
    COMPUTE(0)
    SYNCPT
    if (k0 + 64 < 512) { STAGE(0, k0 + 64) }
    COMPUTE(1)
    SYNCPT
  }
#undef STAGE
#undef SYNCPT
#undef COMPUTE

  // uint u of row holds chans (32*(u>>4)+(u&15), +16)
#pragma unroll
  for (int mb = 0; mb < 2; ++mb) {
    const int row0 = rowbase + wm * 32 + mb * 16 + l16 * 4;
#pragma unroll
    for (int r = 0; r < 4; ++r) {
      const int row = row0 + r;
      if (row < Nk) {
        uint* zp = Zp + ((size_t)kk * 2040 + row) * 128 + (colbase >> 1) + wn * 32 + l15;
        zp[0]  = pkh(acc[mb][0][r], acc[mb][1][r]);
        zp[16] = pkh(acc[mb][2][r], acc[mb][3][r]);
      }
    }
  }
}

// ---------- loss: 16 lanes/row = 2 neg-halves x 8 chan-lanes ----------
#if HAVE_SDOT8
// z signed int4 nibbles; pool biased nibbles un-biased via XOR 0x8 per nibble.
#define DOTN(P) ({                                                              \
    int d_ = 0;                                                                 \
    d_ = sdot8_(zq4[0], P.x ^ 0x88888888u, d_);                                 \
    d_ = sdot8_(zq4[1], P.y ^ 0x88888888u, d_);                                 \
    d_ = sdot8_(zq4[2], P.z ^ 0x88888888u, d_);                                 \
    d_ = sdot8_(zq4[3], P.w ^ 0x88888888u, d_);                                 \
    qsum8i(d_); })
#else
#define DOTN(P) ({                                                              \
    int d0_ = 0, d1_ = 0;                                                       \
    uint e_, o_;                                                                \
    e_ = P.x & 0x0F0F0F0Fu; o_ = (P.x >> 4) & 0x0F0F0F0Fu;                      \
    d0_ = sdot4_(zq[0], e_, d0_); d1_ = sdot4_(zq[4], o_, d1_);                 \
    e_ = P.y & 0x0F0F0F0Fu; o_ = (P.y >> 4) & 0x0F0F0F0Fu;                      \
    d0_ = sdot4_(zq[1], e_, d0_); d1_ = sdot4_(zq[5], o_, d1_);                 \
    e_ = P.z & 0x0F0F0F0Fu; o_ = (P.z >> 4) & 0x0F0F0F0Fu;                      \
    d0_ = sdot4_(zq[2], e_, d0_); d1_ = sdot4_(zq[6], o_, d1_);                 \
    e_ = P.w & 0x0F0F0F0Fu; o_ = (P.w >> 4) & 0x0F0F0F0Fu;                      \
    d0_ = sdot4_(zq[3], e_, d0_); d1_ = sdot4_(zq[7], o_, d1_);                 \
    qsum8i(d0_ + d1_); })
#endif

#define LDB(P, IDX) P = *(const uint4*)(pbase + (size_t)(uint)(IDX) * 32);
#define ACCB(SUM, P) SUM += exp2f(fmaf((float)DOTN(P), kG, c2m));

__global__ __launch_bounds__(256) void loss_kernel(
    const uint* __restrict__ Zp, const uint* __restrict__ pool4,
    const int* __restrict__ neg_idx, float* __restrict__ acc,
    int* __restrict__ cnt, float* __restrict__ out) {
  const int kk = blockIdx.y;
  const int Tk = 255 - kk, Nk = 8 * Tk;
  const int tid = threadIdx.x;
  const int n = blockIdx.x * 16 + (tid >> 4);
  const int l = tid & 15;
  const int h = l >> 3;   // neg half: negs [64h, 64h+64)
  const int g = l & 7;    // chan chunk: chans [32g, 32g+32)
  float row_loss = 0.f;
  if (n < Nk) {
    const uint* zr = Zp + ((size_t)kk * 2040 + n) * 128 + g * 16;
    uint zu[16];
#pragma unroll
    for (int i = 0; i < 4; ++i) *(uint4*)(zu + 4 * i) = *(const uint4*)(zr + 4 * i);
    float zf[32];
#pragma unroll
    for (int c = 0; c < 16; ++c) {
      const half2v hv = h2(zu[c]);
      zf[c] = (float)hv.x;
      zf[16 + c] = (float)hv.y;
    }
    float ss = 0.f;
#pragma unroll
    for (int i = 0; i < 32; ++i) ss = fmaf(zf[i], zf[i], ss);
    ss = dpp_add<0xB1>(ss); ss = dpp_add<0x4E>(ss); ss = dpp_add<0x141>(ss);

#if HAVE_SDOT8
    // quantize z to signed int4 at the pool's global step; nibble n of uint j = chan 8j+n
    const float s_z = rsqrtf(ss) * PQS;
    uint zq4[4];
#pragma unroll
    for (int j = 0; j < 4; ++j) {
      uint w = 0;
#pragma unroll
      for (int n2 = 0; n2 < 8; ++n2) {
        const int q = (int)rintf(fminf(fmaxf(zf[8 * j + n2] * s_z, -7.f), 7.f));
        w |= ((uint)(q & 15)) << (4 * n2);
      }
      zq4[j] = w;
    }
    int nq = 0;
#pragma unroll
    for (int j = 0; j < 4; ++j) nq = sdot8_(zq4[j], zq4[j], nq);
    nq = qsum8i(nq);
    const float kG = (INV_TEMP * L2E * PDELTA) * rsqrtf((float)nq);
    const float c2m = -OFFE;
    const float poseb = 0.f;
#else
    const float s127 = rsqrtf(ss) * 127.f;
    uint zq[8];
#pragma unroll
    for (int t = 0; t < 4; ++t) {
      const uint e0 = (uint)((int)rintf(zf[8 * t]     * s127) & 255);
      const uint e1 = (uint)((int)rintf(zf[8 * t + 2] * s127) & 255);
      const uint e2 = (uint)((int)rintf(zf[8 * t + 4] * s127) & 255);
      const uint e3 = (uint)((int)rintf(zf[8 * t + 6] * s127) & 255);
      zq[t] = e0 | (e1 << 8) | (e2 << 16) | (e3 << 24);
      const uint o0 = (uint)((int)rintf(zf[8 * t + 1] * s127) & 255);
      const uint o1 = (uint)((int)rintf(zf[8 * t + 3] * s127) & 255);
      const uint o2 = (uint)((int)rintf(zf[8 * t + 5] * s127) & 255);
      const uint o3 = (uint)((int)rintf(zf[8 * t + 7] * s127) & 255);
      zq[t + 4] = o0 | (o1 << 8) | (o2 << 16) | (o3 << 24);
    }
    int nq = 0, zs = 0;
#pragma unroll
    for (int t = 0; t < 8; ++t) {
      nq = sdot4_(zq[t], zq[t], nq);
      zs = sdot4_(zq[t], 0x01010101u, zs);
    }
    nq = qsum8i(nq);
    zs = qsum8i(zs);
    const float kG = (INV_TEMP * L2E * PDELTA) * rsqrtf((float)nq);
    const float poseb = -8.f * (float)zs * kG;  // bias term (biased pool)
    const float c2m = poseb - OFFE;
#endif

    const uint* pbase = pool4 + g * 4;
    const int bb = n / Tk, tt = n - bb * Tk;
    uint4 PP;
    LDB(PP, bb * 256 + tt + kk + 1)
    const float pose = fmaf((float)DOTN(PP), kG, poseb);

    const int* ip = neg_idx + ((size_t)kk * 2040 + n) * 128 + h * 64;
    float s0 = 0.f, s1 = 0.f, s2 = 0.f, s3 = 0.f;
    uint4 A, B, C, D, E, F, G, H;
    {
      const int4 iv = *(const int4*)ip;
      LDB(A, iv.x) LDB(B, iv.y) LDB(C, iv.z) LDB(D, iv.w)
    }
    for (int j8 = 0; j8 < 8; ++j8) {
      {  // prefetch odd quad
        const int4 jv = *(const int4*)(ip + j8 * 8 + 4);
        LDB(E, jv.x) LDB(F, jv.y) LDB(G, jv.z) LDB(H, jv.w)
      }
      ACCB(s0, A) ACCB(s1, B) ACCB(s2, C) ACCB(s3, D)
      if (j8 < 7) {  // prefetch next even quad
        const int4 kv = *(const int4*)(ip + j8 * 8 + 8);
        LDB(A, kv.x) LDB(B, kv.y) LDB(C, kv.z) LDB(D, kv.w)
      }
      ACCB(s0, E) ACCB(s1, F) ACCB(s2, G) ACCB(s3, H)
    }
    float sl = (s0 + s1) + (s2 + s3);
    sl = dpp_add<0x140>(sl);  // crosses (h,g)<->(1-h,7-g)
    const float ssum = sl + exp2f(pose - OFFE);
    row_loss = LOGIT_MAX + 0.69314718f * (__log2f(ssum) - pose);
  }
  __shared__ float bl[16];
  if (l == 0) bl[tid >> 4] = row_loss;
  __syncthreads();
  if (tid == 0) {
    float s = 0.f;
#pragma unroll
    for (int i = 0; i < 16; ++i) s += bl[i];
    atomicAdd(&acc[kk], s);
    __threadfence();
    const int old = atomicAdd(cnt, 1);
    if (old == 12 * 128 - 1) {  // last block: finalize
      float tot = 0.f;
#pragma unroll
      for (int k2 = 0; k2 < 12; ++k2)
        tot += atomicAdd(&acc[k2], 0.0f) / (8.0f * (255 - k2));
      out[0] = tot / 12.0f;
    }
  }
}

extern "C" void kernel_launch(void* const* d_in, const int* in_sizes, int n_in,
                              void* d_out, int out_size, void* d_ws, size_t ws_size,
                              hipStream_t stream) {
  const float* ctx = (const float*)d_in[0];   // (8,256,512)
  const float* enc = (const float*)d_in[1];   // (8,256,256)
  const float* W   = (const float*)d_in[2];   // (12,256,512)
  const int*   neg = (const int*)d_in[3];     // (12,2040,128)
  float* out = (float*)d_out;

  char* ws = (char*)d_ws;
  uint*   pool4 = (uint*)(ws);                      // 262,144 B
  ushort* ctxb  = (ushort*)(ws + 262144);           // 2,097,152
  ushort* Wb    = (ushort*)(ws + 2359296);          // 3,145,728
  uint*   Zp    = (uint*)(ws + 5505024);            // 12,533,760
  float*  accb  = (float*)(ws + 18038784);          // 48 B
  int*    cnt   = (int*)(ws + 18038832);            // 4 B

  prep_kernel<<<dim3(1408), dim3(256), 0, stream>>>(ctx, W, enc, ctxb, Wb, pool4, accb, cnt);
  zhat_gemm_kernel<<<dim3(2, 32, 12), dim3(256), 0, stream>>>(ctxb, Wb, Zp);
  loss_kernel<<<dim3(128, 12), dim3(256), 0, stream>>>(Zp, pool4, neg, accb, cnt, out);
}

// Round 15
// 65.852 us; speedup vs baseline: 1.4220x; 1.4220x over previous
//
#include <hip/hip_runtime.h>
#include <hip/hip_bf16.h>

typedef __attribute__((ext_vector_type(8))) short short8;
typedef __attribute__((ext_vector_type(4))) float f32x4;
typedef _Float16 __attribute__((ext_vector_type(2))) half2v;

#define INV_TEMP 14.285714285714286f
#define LOGIT_MAX 14.2857143f
#define L2E 1.44269504f
#define OFFE (LOGIT_MAX * L2E)
#define PCLIP 0.23f
#define PDELTA (PCLIP / 7.f)
#define PQS (7.f / PCLIP)

__device__ __forceinline__ ushort bf16c(float f) {
  uint u = __float_as_uint(f);
  uint r = (u + 0x7fffu + ((u >> 16) & 1u)) >> 16;
  return (ushort)r;
}
__device__ __forceinline__ uint pk2(float a, float b) {
  return (uint)bf16c(a) | ((uint)bf16c(b) << 16);
}
__device__ __forceinline__ uint pkh(float a, float b) {
  return __builtin_bit_cast(uint, __builtin_amdgcn_cvt_pkrtz(a, b));
}
__device__ __forceinline__ half2v h2(uint u) {
  return __builtin_bit_cast(half2v, u);
}
__device__ __forceinline__ int sdot4_(uint a, uint b, int c) {
  return __builtin_amdgcn_sdot4((int)a, (int)b, c, false);
}
// async global->LDS, 16B per lane; LDS dest = wave-uniform base + lane*16
__device__ __forceinline__ void gl_lds16(const void* g, void* l) {
  __builtin_amdgcn_global_load_lds(
      (const __attribute__((address_space(1))) void*)g,
      (__attribute__((address_space(3))) void*)l, 16, 0, 0);
}

template <int CTRL>
__device__ __forceinline__ float dpp_add(float v) {
  const int x = __builtin_amdgcn_mov_dpp(__float_as_int(v), CTRL, 0xF, 0xF, true);
  return v + __int_as_float(x);
}
template <int CTRL>
__device__ __forceinline__ int dpp_addi(int v) {
  return v + __builtin_amdgcn_mov_dpp(v, CTRL, 0xF, 0xF, true);
}
__device__ __forceinline__ float qsum16(float v) {
  v = dpp_add<0xB1>(v);
  v = dpp_add<0x4E>(v);
  v = dpp_add<0x141>(v);
  v = dpp_add<0x140>(v);
  return v;
}
__device__ __forceinline__ int qsum8i(int v) {
  v = dpp_addi<0xB1>(v);
  v = dpp_addi<0x4E>(v);
  v = dpp_addi<0x141>(v);
  return v;
}

// ---------- prep: cvt ctx (blocks [0,512)), cvt W ([512,1280)), pool int4 ([1280,1408)) ----------
__global__ __launch_bounds__(256) void prep_kernel(
    const float* __restrict__ ctx, const float* __restrict__ W,
    const float* __restrict__ enc, ushort* __restrict__ ctxb,
    ushort* __restrict__ Wb, uint* __restrict__ pool4,
    float* __restrict__ acc) {
  const int bid = blockIdx.x;
  const int tid = threadIdx.x;
  if (bid < 1280) {
    const float* in;
    ushort* out;
    size_t i;
    if (bid < 512) { in = ctx; out = ctxb; i = (size_t)bid * 256 + tid; }
    else           { in = W;   out = Wb;   i = (size_t)(bid - 512) * 256 + tid; }
    const float4 a = *(const float4*)(in + i * 8);
    const float4 b = *(const float4*)(in + i * 8 + 4);
    const uint4 o = make_uint4(pk2(a.x, a.y), pk2(a.z, a.w), pk2(b.x, b.y), pk2(b.z, b.w));
    *(uint4*)(out + i * 8) = o;
    return;
  }
  // pool: p' = clamp(rint(e_norm/PDELTA),-7,7)+8, nibble n of uint j = chan 8j+n
  if (bid == 1280 && tid < 12) acc[tid] = 0.f;
  const int grp = tid >> 4, lane = tid & 15;
  const int r = (bid - 1280) * 16 + grp;  // 0..2047
  const float* src = enc + (size_t)r * 256 + lane * 16;
  float4 v0 = *(const float4*)(src);
  float4 v1 = *(const float4*)(src + 4);
  float4 v2 = *(const float4*)(src + 8);
  float4 v3 = *(const float4*)(src + 12);
  float c[16] = {v0.x, v0.y, v0.z, v0.w, v1.x, v1.y, v1.z, v1.w,
                 v2.x, v2.y, v2.z, v2.w, v3.x, v3.y, v3.z, v3.w};
  float ss = 0.f;
#pragma unroll
  for (int i = 0; i < 16; ++i) ss = fmaf(c[i], c[i], ss);
  ss = qsum16(ss);
  const float qs = rsqrtf(ss) * PQS;
  uint w0 = 0, w1 = 0;
#pragma unroll
  for (int n = 0; n < 8; ++n) {
    const int q0 = (int)rintf(fminf(fmaxf(c[n] * qs, -7.f), 7.f)) + 8;
    const int q1 = (int)rintf(fminf(fmaxf(c[8 + n] * qs, -7.f), 7.f)) + 8;
    w0 |= (uint)q0 << (4 * n);
    w1 |= (uint)q1 << (4 * n);
  }
  *(uint2*)(pool4 + (size_t)r * 32 + lane * 2) = make_uint2(w0, w1);
}

// ---------- z_hat[k] = ctx_rows @ W[k]^T, bf16 MFMA, 2-phase double-buffered gl_lds ----------
__global__ __launch_bounds__(256) void zhat_gemm_kernel(
    const ushort* __restrict__ ctxb, const ushort* __restrict__ Wb,
    uint* __restrict__ Zp) {
  const int kk = blockIdx.z;
  const int Tk = 255 - kk, Nk = 8 * Tk;
  const int rowbase = blockIdx.y * 64;
  if (rowbase >= Nk) return;
  const int colbase = blockIdx.x * 128;

  __shared__ __attribute__((aligned(16))) ushort As[2][64 * 32];    // 2 x 4 KB
  __shared__ __attribute__((aligned(16))) ushort Bs[2][128 * 32];   // 2 x 8 KB

  const int tid = threadIdx.x;
  const int wid = tid >> 6, lane = tid & 63;
  const int arow = tid & 63;
  int n = rowbase + arow;
  if (n >= Nk) n = Nk - 1;  // clamp (valid memory; result rows discarded)
  const int bb = n / Tk, tt = n - bb * Tk;
  const ushort* aptr = ctxb + ((size_t)(bb * 256 + tt)) * 512 + (tid >> 6) * 8;
  const int brow = tid & 127;
  const ushort* bptr = Wb + ((size_t)kk * 256 + colbase + brow) * 512 + (tid >> 7) * 8;

  const int wm = wid >> 1, wn = wid & 1;
  const int l15 = lane & 15, l16 = lane >> 4;
  const int wboff = wid * 1024;  // byte offset of this wave's stage quarter

  f32x4 acc[2][4];
#pragma unroll
  for (int i = 0; i < 2; ++i)
#pragma unroll
    for (int j = 0; j < 4; ++j) acc[i][j] = (f32x4){0.f, 0.f, 0.f, 0.f};

  const size_t aoff = (size_t)(l16 * 64 + wm * 32 + l15) * 8;   // ushort units
  const size_t boff = (size_t)(l16 * 128 + wn * 64 + l15) * 8;

#define STAGE(B, K0)                                              \
  gl_lds16(aptr + (K0), (char*)As[B] + wboff);                    \
  gl_lds16(bptr + (K0), (char*)Bs[B] + wboff);                    \
  gl_lds16(bptr + (K0) + 16, (char*)Bs[B] + wboff + 4096);

#define SYNCPT                                                    \
  asm volatile("s_waitcnt vmcnt(0)" ::: "memory");                \
  __builtin_amdgcn_s_barrier();                                   \
  __builtin_amdgcn_sched_barrier(0);

#define COMPUTE(B)                                                              \
  {                                                                             \
    const ushort* ar = As[B] + aoff;                                            \
    const ushort* br = Bs[B] + boff;                                            \
    short8 bf[4];                                                               \
    bf[0] = *(const short8*)(br);                                               \
    bf[1] = *(const short8*)(br + 128);                                         \
    bf[2] = *(const short8*)(br + 256);                                         \
    bf[3] = *(const short8*)(br + 384);                                         \
    const short8 a0 = *(const short8*)(ar);                                     \
    const short8 a1 = *(const short8*)(ar + 128);                               \
    _Pragma("unroll")                                                           \
    for (int nb = 0; nb < 4; ++nb) {                                            \
      acc[0][nb] = __builtin_amdgcn_mfma_f32_16x16x32_bf16(a0, bf[nb], acc[0][nb], 0, 0, 0); \
      acc[1][nb] = __builtin_amdgcn_mfma_f32_16x16x32_bf16(a1, bf[nb], acc[1][nb], 0, 0, 0); \
    }                                                                           \
  }

  STAGE(0, 0)
  SYNCPT
  for (int k0 = 0; k0 < 512; k0 += 64) {
    STAGE(1, k0 + 32)
    COMPUTE(0)
    SYNCPT
    if (k0 + 64 < 512) { STAGE(0, k0 + 64) }
    COMPUTE(1)
    SYNCPT
  }
#undef STAGE
#undef SYNCPT
#undef COMPUTE

  // uint u of row holds chans (32*(u>>4)+(u&15), +16)
#pragma unroll
  for (int mb = 0; mb < 2; ++mb) {
    const int row0 = rowbase + wm * 32 + mb * 16 + l16 * 4;
#pragma unroll
    for (int r = 0; r < 4; ++r) {
      const int row = row0 + r;
      if (row < Nk) {
        uint* zp = Zp + ((size_t)kk * 2040 + row) * 128 + (colbase >> 1) + wn * 32 + l15;
        zp[0]  = pkh(acc[mb][0][r], acc[mb][1][r]);
        zp[16] = pkh(acc[mb][2][r], acc[mb][3][r]);
      }
    }
  }
}

// ---------- loss: 16 lanes/row = 2 neg-halves x 8 chan-lanes; int8 z · int4 pool ----------
#define DOTN(P) ({                                                              \
    int d0_ = 0, d1_ = 0;                                                       \
    uint e_, o_;                                                                \
    e_ = P.x & 0x0F0F0F0Fu; o_ = (P.x >> 4) & 0x0F0F0F0Fu;                      \
    d0_ = sdot4_(zq[0], e_, d0_); d1_ = sdot4_(zq[4], o_, d1_);                 \
    e_ = P.y & 0x0F0F0F0Fu; o_ = (P.y >> 4) & 0x0F0F0F0Fu;                      \
    d0_ = sdot4_(zq[1], e_, d0_); d1_ = sdot4_(zq[5], o_, d1_);                 \
    e_ = P.z & 0x0F0F0F0Fu; o_ = (P.z >> 4) & 0x0F0F0F0Fu;                      \
    d0_ = sdot4_(zq[2], e_, d0_); d1_ = sdot4_(zq[6], o_, d1_);                 \
    e_ = P.w & 0x0F0F0F0Fu; o_ = (P.w >> 4) & 0x0F0F0F0Fu;                      \
    d0_ = sdot4_(zq[3], e_, d0_); d1_ = sdot4_(zq[7], o_, d1_);                 \
    qsum8i(d0_ + d1_); })

#define LDB(P, IDX) P = *(const uint4*)(pbase + (size_t)(uint)(IDX) * 32);
#define ACCB(SUM, P) SUM += exp2f(fmaf((float)DOTN(P), kG, c2m));

__global__ __launch_bounds__(256) void loss_kernel(
    const uint* __restrict__ Zp, const uint* __restrict__ pool4,
    const int* __restrict__ neg_idx, float* __restrict__ acc) {
  const int kk = blockIdx.y;
  const int Tk = 255 - kk, Nk = 8 * Tk;
  if ((int)(blockIdx.x * 16) >= Nk) return;
  const int tid = threadIdx.x;
  const int n = blockIdx.x * 16 + (tid >> 4);
  const int l = tid & 15;
  const int h = l >> 3;   // neg half: negs [64h, 64h+64)
  const int g = l & 7;    // chan chunk: chans [32g, 32g+32)
  float row_loss = 0.f;
  if (n < Nk) {
    const uint* zr = Zp + ((size_t)kk * 2040 + n) * 128 + g * 16;
    uint zu[16];
#pragma unroll
    for (int i = 0; i < 4; ++i) *(uint4*)(zu + 4 * i) = *(const uint4*)(zr + 4 * i);
    float zf[32];
#pragma unroll
    for (int c = 0; c < 16; ++c) {
      const half2v hv = h2(zu[c]);
      zf[c] = (float)hv.x;
      zf[16 + c] = (float)hv.y;
    }
    float ss = 0.f;
#pragma unroll
    for (int i = 0; i < 32; ++i) ss = fmaf(zf[i], zf[i], ss);
    ss = dpp_add<0xB1>(ss); ss = dpp_add<0x4E>(ss); ss = dpp_add<0x141>(ss);
    const float s127 = rsqrtf(ss) * 127.f;
    uint zq[8];
#pragma unroll
    for (int t = 0; t < 4; ++t) {
      const uint e0 = (uint)((int)rintf(zf[8 * t]     * s127) & 255);
      const uint e1 = (uint)((int)rintf(zf[8 * t + 2] * s127) & 255);
      const uint e2 = (uint)((int)rintf(zf[8 * t + 4] * s127) & 255);
      const uint e3 = (uint)((int)rintf(zf[8 * t + 6] * s127) & 255);
      zq[t] = e0 | (e1 << 8) | (e2 << 16) | (e3 << 24);
      const uint o0 = (uint)((int)rintf(zf[8 * t + 1] * s127) & 255);
      const uint o1 = (uint)((int)rintf(zf[8 * t + 3] * s127) & 255);
      const uint o2 = (uint)((int)rintf(zf[8 * t + 5] * s127) & 255);
      const uint o3 = (uint)((int)rintf(zf[8 * t + 7] * s127) & 255);
      zq[t + 4] = o0 | (o1 << 8) | (o2 << 16) | (o3 << 24);
    }
    int nq = 0, zs = 0;
#pragma unroll
    for (int t = 0; t < 8; ++t) {
      nq = sdot4_(zq[t], zq[t], nq);
      zs = sdot4_(zq[t], 0x01010101u, zs);
    }
    nq = qsum8i(nq);
    zs = qsum8i(zs);
    const float kG = (INV_TEMP * L2E * PDELTA) * rsqrtf((float)nq);
    const float c2 = -8.f * (float)zs * kG;
    const float c2m = c2 - OFFE;

    const uint* pbase = pool4 + g * 4;
    const int bb = n / Tk, tt = n - bb * Tk;
    uint4 PP;
    LDB(PP, bb * 256 + tt + kk + 1)
    const float pose = fmaf((float)DOTN(PP), kG, c2);

    // this half's 64 negs = 16 idx-quads; idx prefetched 2 iterations ahead,
    // pool gathers double-buffered 8-deep (A-D / E-H).
    const int4* ipq = (const int4*)(neg_idx + ((size_t)kk * 2040 + n) * 128 + h * 64);
    float s0 = 0.f, s1 = 0.f, s2 = 0.f, s3 = 0.f;
    uint4 A, B, C, D, E, F, G, H;
    int4 q[16];
    q[0] = ipq[0]; q[1] = ipq[1]; q[2] = ipq[2]; q[3] = ipq[3];
    LDB(A, q[0].x) LDB(B, q[0].y) LDB(C, q[0].z) LDB(D, q[0].w)
#pragma unroll
    for (int j8 = 0; j8 < 8; ++j8) {
      // gathers for odd quad (idx resident since iter j8-2)
      LDB(E, q[2 * j8 + 1].x) LDB(F, q[2 * j8 + 1].y)
      LDB(G, q[2 * j8 + 1].z) LDB(H, q[2 * j8 + 1].w)
      if (j8 < 6) q[2 * j8 + 4] = ipq[2 * j8 + 4];   // idx prefetch, used iter j8+1
      ACCB(s0, A) ACCB(s1, B) ACCB(s2, C) ACCB(s3, D)
      if (j8 < 7) {
        // gathers for next even quad (idx resident since iter j8-1)
        LDB(A, q[2 * j8 + 2].x) LDB(B, q[2 * j8 + 2].y)
        LDB(C, q[2 * j8 + 2].z) LDB(D, q[2 * j8 + 2].w)
      }
      if (j8 < 6) q[2 * j8 + 5] = ipq[2 * j8 + 5];   // idx prefetch, used iter j8+2
      ACCB(s0, E) ACCB(s1, F) ACCB(s2, G) ACCB(s3, H)
    }
    float sl = (s0 + s1) + (s2 + s3);
    sl = dpp_add<0x140>(sl);  // crosses (h,g)<->(1-h,7-g)
    const float ssum = sl + exp2f(pose - OFFE);
    row_loss = LOGIT_MAX + 0.69314718f * (__log2f(ssum) - pose);
  }
  __shared__ float bl[16];
  if (l == 0) bl[tid >> 4] = row_loss;
  __syncthreads();
  if (tid == 0) {
    float s = 0.f;
#pragma unroll
    for (int i = 0; i < 16; ++i) s += bl[i];
    atomicAdd(&acc[kk], s);
  }
}

__global__ void finalize_kernel(const float* __restrict__ acc,
                                float* __restrict__ out) {
  if (threadIdx.x == 0) {
    float tot = 0.f;
#pragma unroll
    for (int kk = 0; kk < 12; ++kk) tot += acc[kk] / (8.0f * (255 - kk));
    out[0] = tot / 12.0f;
  }
}

extern "C" void kernel_launch(void* const* d_in, const int* in_sizes, int n_in,
                              void* d_out, int out_size, void* d_ws, size_t ws_size,
                              hipStream_t stream) {
  const float* ctx = (const float*)d_in[0];   // (8,256,512)
  const float* enc = (const float*)d_in[1];   // (8,256,256)
  const float* W   = (const float*)d_in[2];   // (12,256,512)
  const int*   neg = (const int*)d_in[3];     // (12,2040,128)
  float* out = (float*)d_out;

  char* ws = (char*)d_ws;
  uint*   pool4 = (uint*)(ws);                      // 262,144 B
  ushort* ctxb  = (ushort*)(ws + 262144);           // 2,097,152
  ushort* Wb    = (ushort*)(ws + 2359296);          // 3,145,728
  uint*   Zp    = (uint*)(ws + 5505024);            // 12,533,760
  float*  accb  = (float*)(ws + 18038784);          // 48 B

  prep_kernel<<<dim3(1408), dim3(256), 0, stream>>>(ctx, W, enc, ctxb, Wb, pool4, accb);
  zhat_gemm_kernel<<<dim3(2, 32, 12), dim3(256), 0, stream>>>(ctxb, Wb, Zp);
  loss_kernel<<<dim3(128, 12), dim3(256), 0, stream>>>(Zp, pool4, neg, accb);
  finalize_kernel<<<dim3(1), dim3(64), 0, stream>>>(accb, out);
}

// Round 16
// 60.951 us; speedup vs baseline: 1.5364x; 1.0804x over previous
//
#include <hip/hip_runtime.h>
#include <hip/hip_bf16.h>

typedef __attribute__((ext_vector_type(8))) short short8;
typedef __attribute__((ext_vector_type(4))) float f32x4;
typedef _Float16 __attribute__((ext_vector_type(2))) half2v;

#define INV_TEMP 14.285714285714286f
#define LOGIT_MAX 14.2857143f
#define L2E 1.44269504f
#define OFFE (LOGIT_MAX * L2E)
#define PCLIP 0.23f
#define PDELTA (PCLIP / 7.f)
#define PQS (7.f / PCLIP)

__device__ __forceinline__ ushort bf16c(float f) {
  uint u = __float_as_uint(f);
  uint r = (u + 0x7fffu + ((u >> 16) & 1u)) >> 16;
  return (ushort)r;
}
__device__ __forceinline__ uint pk2(float a, float b) {
  return (uint)bf16c(a) | ((uint)bf16c(b) << 16);
}
__device__ __forceinline__ uint pkh(float a, float b) {
  return __builtin_bit_cast(uint, __builtin_amdgcn_cvt_pkrtz(a, b));
}
__device__ __forceinline__ half2v h2(uint u) {
  return __builtin_bit_cast(half2v, u);
}
__device__ __forceinline__ int sdot4_(uint a, uint b, int c) {
  return __builtin_amdgcn_sdot4((int)a, (int)b, c, false);
}
// async global->LDS, 16B per lane; LDS dest = wave-uniform base + lane*16
__device__ __forceinline__ void gl_lds16(const void* g, void* l) {
  __builtin_amdgcn_global_load_lds(
      (const __attribute__((address_space(1))) void*)g,
      (__attribute__((address_space(3))) void*)l, 16, 0, 0);
}

template <int CTRL>
__device__ __forceinline__ float dpp_add(float v) {
  const int x = __builtin_amdgcn_mov_dpp(__float_as_int(v), CTRL, 0xF, 0xF, true);
  return v + __int_as_float(x);
}
template <int CTRL>
__device__ __forceinline__ int dpp_addi(int v) {
  return v + __builtin_amdgcn_mov_dpp(v, CTRL, 0xF, 0xF, true);
}
template <int CTRL>
__device__ __forceinline__ int dpp_movi(int v) {
  return __builtin_amdgcn_mov_dpp(v, CTRL, 0xF, 0xF, true);
}
__device__ __forceinline__ float qsum16(float v) {
  v = dpp_add<0xB1>(v);
  v = dpp_add<0x4E>(v);
  v = dpp_add<0x141>(v);
  v = dpp_add<0x140>(v);
  return v;
}
__device__ __forceinline__ int qsum8i(int v) {
  v = dpp_addi<0xB1>(v);
  v = dpp_addi<0x4E>(v);
  v = dpp_addi<0x141>(v);
  return v;
}

// ---------- prep: cvt ctx (blocks [0,512)), cvt W ([512,1280)), pool int4 ([1280,1408)) ----------
__global__ __launch_bounds__(256) void prep_kernel(
    const float* __restrict__ ctx, const float* __restrict__ W,
    const float* __restrict__ enc, ushort* __restrict__ ctxb,
    ushort* __restrict__ Wb, uint* __restrict__ pool4,
    float* __restrict__ acc) {
  const int bid = blockIdx.x;
  const int tid = threadIdx.x;
  if (bid < 1280) {
    const float* in;
    ushort* out;
    size_t i;
    if (bid < 512) { in = ctx; out = ctxb; i = (size_t)bid * 256 + tid; }
    else           { in = W;   out = Wb;   i = (size_t)(bid - 512) * 256 + tid; }
    const float4 a = *(const float4*)(in + i * 8);
    const float4 b = *(const float4*)(in + i * 8 + 4);
    const uint4 o = make_uint4(pk2(a.x, a.y), pk2(a.z, a.w), pk2(b.x, b.y), pk2(b.z, b.w));
    *(uint4*)(out + i * 8) = o;
    return;
  }
  // pool: p' = clamp(rint(e_norm/PDELTA),-7,7)+8, nibble n of uint j = chan 8j+n
  if (bid == 1280 && tid < 12) acc[tid] = 0.f;
  const int grp = tid >> 4, lane = tid & 15;
  const int r = (bid - 1280) * 16 + grp;  // 0..2047
  const float* src = enc + (size_t)r * 256 + lane * 16;
  float4 v0 = *(const float4*)(src);
  float4 v1 = *(const float4*)(src + 4);
  float4 v2 = *(const float4*)(src + 8);
  float4 v3 = *(const float4*)(src + 12);
  float c[16] = {v0.x, v0.y, v0.z, v0.w, v1.x, v1.y, v1.z, v1.w,
                 v2.x, v2.y, v2.z, v2.w, v3.x, v3.y, v3.z, v3.w};
  float ss = 0.f;
#pragma unroll
  for (int i = 0; i < 16; ++i) ss = fmaf(c[i], c[i], ss);
  ss = qsum16(ss);
  const float qs = rsqrtf(ss) * PQS;
  uint w0 = 0, w1 = 0;
#pragma unroll
  for (int n = 0; n < 8; ++n) {
    const int q0 = (int)rintf(fminf(fmaxf(c[n] * qs, -7.f), 7.f)) + 8;
    const int q1 = (int)rintf(fminf(fmaxf(c[8 + n] * qs, -7.f), 7.f)) + 8;
    w0 |= (uint)q0 << (4 * n);
    w1 |= (uint)q1 << (4 * n);
  }
  *(uint2*)(pool4 + (size_t)r * 32 + lane * 2) = make_uint2(w0, w1);
}

// ---------- z_hat[k] = ctx_rows @ W[k]^T, bf16 MFMA, 2-phase double-buffered gl_lds ----------
__global__ __launch_bounds__(256) void zhat_gemm_kernel(
    const ushort* __restrict__ ctxb, const ushort* __restrict__ Wb,
    uint* __restrict__ Zp) {
  const int kk = blockIdx.z;
  const int Tk = 255 - kk, Nk = 8 * Tk;
  const int rowbase = blockIdx.y * 64;
  if (rowbase >= Nk) return;
  const int colbase = blockIdx.x * 128;

  __shared__ __attribute__((aligned(16))) ushort As[2][64 * 32];    // 2 x 4 KB
  __shared__ __attribute__((aligned(16))) ushort Bs[2][128 * 32];   // 2 x 8 KB

  const int tid = threadIdx.x;
  const int wid = tid >> 6, lane = tid & 63;
  const int arow = tid & 63;
  int n = rowbase + arow;
  if (n >= Nk) n = Nk - 1;  // clamp (valid memory; result rows discarded)
  const int bb = n / Tk, tt = n - bb * Tk;
  const ushort* aptr = ctxb + ((size_t)(bb * 256 + tt)) * 512 + (tid >> 6) * 8;
  const int brow = tid & 127;
  const ushort* bptr = Wb + ((size_t)kk * 256 + colbase + brow) * 512 + (tid >> 7) * 8;

  const int wm = wid >> 1, wn = wid & 1;
  const int l15 = lane & 15, l16 = lane >> 4;
  const int wboff = wid * 1024;  // byte offset of this wave's stage quarter

  f32x4 acc[2][4];
#pragma unroll
  for (int i = 0; i < 2; ++i)
#pragma unroll
    for (int j = 0; j < 4; ++j) acc[i][j] = (f32x4){0.f, 0.f, 0.f, 0.f};

  const size_t aoff = (size_t)(l16 * 64 + wm * 32 + l15) * 8;   // ushort units
  const size_t boff = (size_t)(l16 * 128 + wn * 64 + l15) * 8;

#define STAGE(B, K0)                                              \
  gl_lds16(aptr + (K0), (char*)As[B] + wboff);                    \
  gl_lds16(bptr + (K0), (char*)Bs[B] + wboff);                    \
  gl_lds16(bptr + (K0) + 16, (char*)Bs[B] + wboff + 4096);

#define SYNCPT                                                    \
  asm volatile("s_waitcnt vmcnt(0)" ::: "memory");                \
  __builtin_amdgcn_s_barrier();                                   \
  __builtin_amdgcn_sched_barrier(0);

#define COMPUTE(B)                                                              \
  {                                                                             \
    const ushort* ar = As[B] + aoff;                                            \
    const ushort* br = Bs[B] + boff;                                            \
    short8 bf[4];                                                               \
    bf[0] = *(const short8*)(br);                                               \
    bf[1] = *(const short8*)(br + 128);                                         \
    bf[2] = *(const short8*)(br + 256);                                         \
    bf[3] = *(const short8*)(br + 384);                                         \
    const short8 a0 = *(const short8*)(ar);                                     \
    const short8 a1 = *(const short8*)(ar + 128);                               \
    _Pragma("unroll")                                                           \
    for (int nb = 0; nb < 4; ++nb) {                                            \
      acc[0][nb] = __builtin_amdgcn_mfma_f32_16x16x32_bf16(a0, bf[nb], acc[0][nb], 0, 0, 0); \
      acc[1][nb] = __builtin_amdgcn_mfma_f32_16x16x32_bf16(a1, bf[nb], acc[1][nb], 0, 0, 0); \
    }                                                                           \
  }

  STAGE(0, 0)
  SYNCPT
  for (int k0 = 0; k0 < 512; k0 += 64) {
    STAGE(1, k0 + 32)
    COMPUTE(0)
    SYNCPT
    if (k0 + 64 < 512) { STAGE(0, k0 + 64) }
    COMPUTE(1)
    SYNCPT
  }
#undef STAGE
#undef SYNCPT
#undef COMPUTE

  // uint u of row holds chans (32*(u>>4)+(u&15), +16)
#pragma unroll
  for (int mb = 0; mb < 2; ++mb) {
    const int row0 = rowbase + wm * 32 + mb * 16 + l16 * 4;
#pragma unroll
    for (int r = 0; r < 4; ++r) {
      const int row = row0 + r;
      if (row < Nk) {
        uint* zp = Zp + ((size_t)kk * 2040 + row) * 128 + (colbase >> 1) + wn * 32 + l15;
        zp[0]  = pkh(acc[mb][0][r], acc[mb][1][r]);
        zp[16] = pkh(acc[mb][2][r], acc[mb][3][r]);
      }
    }
  }
}

// ---------- loss: 16 lanes/row = 2 neg-halves x 8 chan-lanes; int8 z · int4 pool ----------
// Partial dot (no cross-lane reduce): lane's 32 chans vs one neg's 32-chan slice.
#define PDOT(P) ({                                                              \
    int d0_ = 0, d1_ = 0;                                                       \
    uint e_, o_;                                                                \
    e_ = P.x & 0x0F0F0F0Fu; o_ = (P.x >> 4) & 0x0F0F0F0Fu;                      \
    d0_ = sdot4_(zq[0], e_, d0_); d1_ = sdot4_(zq[4], o_, d1_);                 \
    e_ = P.y & 0x0F0F0F0Fu; o_ = (P.y >> 4) & 0x0F0F0F0Fu;                      \
    d0_ = sdot4_(zq[1], e_, d0_); d1_ = sdot4_(zq[5], o_, d1_);                 \
    e_ = P.z & 0x0F0F0F0Fu; o_ = (P.z >> 4) & 0x0F0F0F0Fu;                      \
    d0_ = sdot4_(zq[2], e_, d0_); d1_ = sdot4_(zq[6], o_, d1_);                 \
    e_ = P.w & 0x0F0F0F0Fu; o_ = (P.w >> 4) & 0x0F0F0F0Fu;                      \
    d0_ = sdot4_(zq[3], e_, d0_); d1_ = sdot4_(zq[7], o_, d1_);                 \
    d0_ + d1_; })

#define DOTN(P) ({ int dd_ = PDOT(P); qsum8i(dd_); })

#define LDB(P, IDX) P = *(const uint4*)(pbase + (size_t)(uint)(IDX) * 32);

// 3-round butterfly over the 8 chan-lanes: from 8 per-lane partials (pd0..pd7)
// to one FULL integer dot per lane (lane g of each quad-pair holds a distinct
// neg; partition verified: quad0 lanes 0-3 -> negs 0-3, quad1 lanes 7..4 -> 4..7).
// Selects keyed on mirror-canonical index mu so the 0x141 mirror round aligns.
#define BFLY_ACC                                                                \
  {                                                                             \
    int x_, y_, u0_, u1_, u2_, u3_, r0_, r1_, full_;                            \
    x_ = sA ? pd1 : pd0; y_ = sA ? pd0 : pd1; u0_ = x_ + dpp_movi<0xB1>(y_);    \
    x_ = sA ? pd3 : pd2; y_ = sA ? pd2 : pd3; u1_ = x_ + dpp_movi<0xB1>(y_);    \
    x_ = sA ? pd5 : pd4; y_ = sA ? pd4 : pd5; u2_ = x_ + dpp_movi<0xB1>(y_);    \
    x_ = sA ? pd7 : pd6; y_ = sA ? pd6 : pd7; u3_ = x_ + dpp_movi<0xB1>(y_);    \
    x_ = sB ? u1_ : u0_; y_ = sB ? u0_ : u1_; r0_ = x_ + dpp_movi<0x4E>(y_);    \
    x_ = sB ? u3_ : u2_; y_ = sB ? u2_ : u3_; r1_ = x_ + dpp_movi<0x4E>(y_);    \
    x_ = sC ? r1_ : r0_; y_ = sC ? r0_ : r1_; full_ = x_ + dpp_movi<0x141>(y_); \
    s = fmaf(exp2f(fmaf((float)full_, kG, c2m)), 1.f, s);                       \
  }

__global__ __launch_bounds__(256) void loss_kernel(
    const uint* __restrict__ Zp, const uint* __restrict__ pool4,
    const int* __restrict__ neg_idx, float* __restrict__ acc) {
  const int kk = blockIdx.y;
  const int Tk = 255 - kk, Nk = 8 * Tk;
  if ((int)(blockIdx.x * 16) >= Nk) return;
  const int tid = threadIdx.x;
  const int n = blockIdx.x * 16 + (tid >> 4);
  const int l = tid & 15;
  const int h = l >> 3;   // neg half: negs [64h, 64h+64)
  const int g = l & 7;    // chan chunk: chans [32g, 32g+32)
  float row_loss = 0.f;
  if (n < Nk) {
    const uint* zr = Zp + ((size_t)kk * 2040 + n) * 128 + g * 16;
    uint zu[16];
#pragma unroll
    for (int i = 0; i < 4; ++i) *(uint4*)(zu + 4 * i) = *(const uint4*)(zr + 4 * i);
    float zf[32];
#pragma unroll
    for (int c = 0; c < 16; ++c) {
      const half2v hv = h2(zu[c]);
      zf[c] = (float)hv.x;
      zf[16 + c] = (float)hv.y;
    }
    float ss = 0.f;
#pragma unroll
    for (int i = 0; i < 32; ++i) ss = fmaf(zf[i], zf[i], ss);
    ss = dpp_add<0xB1>(ss); ss = dpp_add<0x4E>(ss); ss = dpp_add<0x141>(ss);
    const float s127 = rsqrtf(ss) * 127.f;
    uint zq[8];
#pragma unroll
    for (int t = 0; t < 4; ++t) {
      const uint e0 = (uint)((int)rintf(zf[8 * t]     * s127) & 255);
      const uint e1 = (uint)((int)rintf(zf[8 * t + 2] * s127) & 255);
      const uint e2 = (uint)((int)rintf(zf[8 * t + 4] * s127) & 255);
      const uint e3 = (uint)((int)rintf(zf[8 * t + 6] * s127) & 255);
      zq[t] = e0 | (e1 << 8) | (e2 << 16) | (e3 << 24);
      const uint o0 = (uint)((int)rintf(zf[8 * t + 1] * s127) & 255);
      const uint o1 = (uint)((int)rintf(zf[8 * t + 3] * s127) & 255);
      const uint o2 = (uint)((int)rintf(zf[8 * t + 5] * s127) & 255);
      const uint o3 = (uint)((int)rintf(zf[8 * t + 7] * s127) & 255);
      zq[t + 4] = o0 | (o1 << 8) | (o2 << 16) | (o3 << 24);
    }
    int nq = 0, zs = 0;
#pragma unroll
    for (int t = 0; t < 8; ++t) {
      nq = sdot4_(zq[t], zq[t], nq);
      zs = sdot4_(zq[t], 0x01010101u, zs);
    }
    nq = qsum8i(nq);
    zs = qsum8i(zs);
    const float kG = (INV_TEMP * L2E * PDELTA) * rsqrtf((float)nq);
    const float c2 = -8.f * (float)zs * kG;
    const float c2m = c2 - OFFE;

    const uint* pbase = pool4 + g * 4;
    const int bb = n / Tk, tt = n - bb * Tk;
    uint4 PP;
    LDB(PP, bb * 256 + tt + kk + 1)
    const float pose = fmaf((float)DOTN(PP), kG, c2);

    // butterfly select masks (mirror-canonical index)
    const int mu = (g & 4) ? (7 - g) : g;
    const bool sA = (mu & 1) != 0;
    const bool sB = (mu & 2) != 0;
    const bool sC = (g & 4) != 0;

    // this half's 64 negs = 16 idx-quads; idx prefetched 2 iterations ahead,
    // pool gathers double-buffered 8-deep (A-D / E-H).
    const int4* ipq = (const int4*)(neg_idx + ((size_t)kk * 2040 + n) * 128 + h * 64);
    float s = 0.f;
    uint4 A, B, C, D, E, F, G, H;
    int4 q[16];
    q[0] = ipq[0]; q[1] = ipq[1]; q[2] = ipq[2]; q[3] = ipq[3];
    LDB(A, q[0].x) LDB(B, q[0].y) LDB(C, q[0].z) LDB(D, q[0].w)
#pragma unroll
    for (int j8 = 0; j8 < 8; ++j8) {
      // gathers for odd quad (idx resident since iter j8-2)
      LDB(E, q[2 * j8 + 1].x) LDB(F, q[2 * j8 + 1].y)
      LDB(G, q[2 * j8 + 1].z) LDB(H, q[2 * j8 + 1].w)
      if (j8 < 6) q[2 * j8 + 4] = ipq[2 * j8 + 4];   // idx prefetch
      const int pd0 = PDOT(A), pd1 = PDOT(B), pd2 = PDOT(C), pd3 = PDOT(D);
      if (j8 < 7) {
        LDB(A, q[2 * j8 + 2].x) LDB(B, q[2 * j8 + 2].y)
        LDB(C, q[2 * j8 + 2].z) LDB(D, q[2 * j8 + 2].w)
      }
      if (j8 < 6) q[2 * j8 + 5] = ipq[2 * j8 + 5];   // idx prefetch
      const int pd4 = PDOT(E), pd5 = PDOT(F), pd6 = PDOT(G), pd7 = PDOT(H);
      BFLY_ACC
    }
    // s holds distinct negs per lane; sum all 16 lanes of the row group
    const float sl = qsum16(s);
    const float ssum = sl + exp2f(pose - OFFE);
    row_loss = LOGIT_MAX + 0.69314718f * (__log2f(ssum) - pose);
  }
  __shared__ float bl[16];
  if (l == 0) bl[tid >> 4] = row_loss;
  __syncthreads();
  if (tid == 0) {
    float s2 = 0.f;
#pragma unroll
    for (int i = 0; i < 16; ++i) s2 += bl[i];
    atomicAdd(&acc[kk], s2);
  }
}

__global__ void finalize_kernel(const float* __restrict__ acc,
                                float* __restrict__ out) {
  if (threadIdx.x == 0) {
    float tot = 0.f;
#pragma unroll
    for (int kk = 0; kk < 12; ++kk) tot += acc[kk] / (8.0f * (255 - kk));
    out[0] = tot / 12.0f;
  }
}

extern "C" void kernel_launch(void* const* d_in, const int* in_sizes, int n_in,
                              void* d_out, int out_size, void* d_ws, size_t ws_size,
                              hipStream_t stream) {
  const float* ctx = (const float*)d_in[0];   // (8,256,512)
  const float* enc = (const float*)d_in[1];   // (8,256,256)
  const float* W   = (const float*)d_in[2];   // (12,256,512)
  const int*   neg = (const int*)d_in[3];     // (12,2040,128)
  float* out = (float*)d_out;

  char* ws = (char*)d_ws;
  uint*   pool4 = (uint*)(ws);                      // 262,144 B
  ushort* ctxb  = (ushort*)(ws + 262144);           // 2,097,152
  ushort* Wb    = (ushort*)(ws + 2359296);          // 3,145,728
  uint*   Zp    = (uint*)(ws + 5505024);            // 12,533,760
  float*  accb  = (float*)(ws + 18038784);          // 48 B

  prep_kernel<<<dim3(1408), dim3(256), 0, stream>>>(ctx, W, enc, ctxb, Wb, pool4, accb);
  zhat_gemm_kernel<<<dim3(2, 32, 12), dim3(256), 0, stream>>>(ctxb, Wb, Zp);
  loss_kernel<<<dim3(128, 12), dim3(256), 0, stream>>>(Zp, pool4, neg, accb);
  finalize_kernel<<<dim3(1), dim3(64), 0, stream>>>(accb, out);
}

// Round 17
// 60.180 us; speedup vs baseline: 1.5561x; 1.0128x over previous
//
#include <hip/hip_runtime.h>
#include <hip/hip_bf16.h>

typedef __attribute__((ext_vector_type(8))) short short8;
typedef __attribute__((ext_vector_type(4))) float f32x4;
typedef _Float16 __attribute__((ext_vector_type(2))) half2v;

#define INV_TEMP 14.285714285714286f
#define LOGIT_MAX 14.2857143f
#define L2E 1.44269504f
#define OFFE (LOGIT_MAX * L2E)
#define PCLIP 0.23f
#define PDELTA (PCLIP / 7.f)
#define PQS (7.f / PCLIP)

#if __has_builtin(__builtin_amdgcn_sdot8)
#define HAVE_SDOT8 1
#else
#define HAVE_SDOT8 0
#endif

__device__ __forceinline__ ushort bf16c(float f) {
  uint u = __float_as_uint(f);
  uint r = (u + 0x7fffu + ((u >> 16) & 1u)) >> 16;
  return (ushort)r;
}
__device__ __forceinline__ uint pk2(float a, float b) {
  return (uint)bf16c(a) | ((uint)bf16c(b) << 16);
}
__device__ __forceinline__ uint pkh(float a, float b) {
  return __builtin_bit_cast(uint, __builtin_amdgcn_cvt_pkrtz(a, b));
}
__device__ __forceinline__ half2v h2(uint u) {
  return __builtin_bit_cast(half2v, u);
}
__device__ __forceinline__ int sdot4_(uint a, uint b, int c) {
  return __builtin_amdgcn_sdot4((int)a, (int)b, c, false);
}
#if HAVE_SDOT8
__device__ __forceinline__ int sdot8_(uint a, uint b, int c) {
  return __builtin_amdgcn_sdot8((int)a, (int)b, c, false);
}
#endif
// async global->LDS, 16B per lane; LDS dest = wave-uniform base + lane*16
__device__ __forceinline__ void gl_lds16(const void* g, void* l) {
  __builtin_amdgcn_global_load_lds(
      (const __attribute__((address_space(1))) void*)g,
      (__attribute__((address_space(3))) void*)l, 16, 0, 0);
}

template <int CTRL>
__device__ __forceinline__ float dpp_add(float v) {
  const int x = __builtin_amdgcn_mov_dpp(__float_as_int(v), CTRL, 0xF, 0xF, true);
  return v + __int_as_float(x);
}
template <int CTRL>
__device__ __forceinline__ int dpp_addi(int v) {
  return v + __builtin_amdgcn_mov_dpp(v, CTRL, 0xF, 0xF, true);
}
template <int CTRL>
__device__ __forceinline__ int dpp_movi(int v) {
  return __builtin_amdgcn_mov_dpp(v, CTRL, 0xF, 0xF, true);
}
__device__ __forceinline__ float qsum16(float v) {
  v = dpp_add<0xB1>(v);
  v = dpp_add<0x4E>(v);
  v = dpp_add<0x141>(v);
  v = dpp_add<0x140>(v);
  return v;
}
__device__ __forceinline__ int qsum8i(int v) {
  v = dpp_addi<0xB1>(v);
  v = dpp_addi<0x4E>(v);
  v = dpp_addi<0x141>(v);
  return v;
}

// ---------- prep: cvt ctx (blocks [0,512)), cvt W ([512,1280)), pool int4 ([1280,1408)) ----------
__global__ __launch_bounds__(256) void prep_kernel(
    const float* __restrict__ ctx, const float* __restrict__ W,
    const float* __restrict__ enc, ushort* __restrict__ ctxb,
    ushort* __restrict__ Wb, uint* __restrict__ pool4,
    float* __restrict__ acc) {
  const int bid = blockIdx.x;
  const int tid = threadIdx.x;
  if (bid < 1280) {
    const float* in;
    ushort* out;
    size_t i;
    if (bid < 512) { in = ctx; out = ctxb; i = (size_t)bid * 256 + tid; }
    else           { in = W;   out = Wb;   i = (size_t)(bid - 512) * 256 + tid; }
    const float4 a = *(const float4*)(in + i * 8);
    const float4 b = *(const float4*)(in + i * 8 + 4);
    const uint4 o = make_uint4(pk2(a.x, a.y), pk2(a.z, a.w), pk2(b.x, b.y), pk2(b.z, b.w));
    *(uint4*)(out + i * 8) = o;
    return;
  }
  // pool: p' = clamp(rint(e_norm/PDELTA),-7,7)+8, nibble n of uint j = chan 8j+n
  if (bid == 1280 && tid < 12) acc[tid] = 0.f;
  const int grp = tid >> 4, lane = tid & 15;
  const int r = (bid - 1280) * 16 + grp;  // 0..2047
  const float* src = enc + (size_t)r * 256 + lane * 16;
  float4 v0 = *(const float4*)(src);
  float4 v1 = *(const float4*)(src + 4);
  float4 v2 = *(const float4*)(src + 8);
  float4 v3 = *(const float4*)(src + 12);
  float c[16] = {v0.x, v0.y, v0.z, v0.w, v1.x, v1.y, v1.z, v1.w,
                 v2.x, v2.y, v2.z, v2.w, v3.x, v3.y, v3.z, v3.w};
  float ss = 0.f;
#pragma unroll
  for (int i = 0; i < 16; ++i) ss = fmaf(c[i], c[i], ss);
  ss = qsum16(ss);
  const float qs = rsqrtf(ss) * PQS;
  uint w0 = 0, w1 = 0;
#pragma unroll
  for (int n = 0; n < 8; ++n) {
    const int q0 = (int)rintf(fminf(fmaxf(c[n] * qs, -7.f), 7.f)) + 8;
    const int q1 = (int)rintf(fminf(fmaxf(c[8 + n] * qs, -7.f), 7.f)) + 8;
    w0 |= (uint)q0 << (4 * n);
    w1 |= (uint)q1 << (4 * n);
  }
  *(uint2*)(pool4 + (size_t)r * 32 + lane * 2) = make_uint2(w0, w1);
}

// ---------- z_hat[k] = ctx_rows @ W[k]^T, bf16 MFMA, 2-phase double-buffered gl_lds ----------
__global__ __launch_bounds__(256) void zhat_gemm_kernel(
    const ushort* __restrict__ ctxb, const ushort* __restrict__ Wb,
    uint* __restrict__ Zp) {
  const int kk = blockIdx.z;
  const int Tk = 255 - kk, Nk = 8 * Tk;
  const int rowbase = blockIdx.y * 64;
  if (rowbase >= Nk) return;
  const int colbase = blockIdx.x * 128;

  __shared__ __attribute__((aligned(16))) ushort As[2][64 * 32];    // 2 x 4 KB
  __shared__ __attribute__((aligned(16))) ushort Bs[2][128 * 32];   // 2 x 8 KB

  const int tid = threadIdx.x;
  const int wid = tid >> 6, lane = tid & 63;
  const int arow = tid & 63;
  int n = rowbase + arow;
  if (n >= Nk) n = Nk - 1;  // clamp (valid memory; result rows discarded)
  const int bb = n / Tk, tt = n - bb * Tk;
  const ushort* aptr = ctxb + ((size_t)(bb * 256 + tt)) * 512 + (tid >> 6) * 8;
  const int brow = tid & 127;
  const ushort* bptr = Wb + ((size_t)kk * 256 + colbase + brow) * 512 + (tid >> 7) * 8;

  const int wm = wid >> 1, wn = wid & 1;
  const int l15 = lane & 15, l16 = lane >> 4;
  const int wboff = wid * 1024;  // byte offset of this wave's stage quarter

  f32x4 acc[2][4];
#pragma unroll
  for (int i = 0; i < 2; ++i)
#pragma unroll
    for (int j = 0; j < 4; ++j) acc[i][j] = (f32x4){0.f, 0.f, 0.f, 0.f};

  const size_t aoff = (size_t)(l16 * 64 + wm * 32 + l15) * 8;   // ushort units
  const size_t boff = (size_t)(l16 * 128 + wn * 64 + l15) * 8;

#define STAGE(B, K0)                                              \
  gl_lds16(aptr + (K0), (char*)As[B] + wboff);                    \
  gl_lds16(bptr + (K0), (char*)Bs[B] + wboff);                    \
  gl_lds16(bptr + (K0) + 16, (char*)Bs[B] + wboff + 4096);

#define SYNCPT                                                    \
  asm volatile("s_waitcnt vmcnt(0)" ::: "memory");                \
  __builtin_amdgcn_s_barrier();                                   \
  __builtin_amdgcn_sched_barrier(0);

#define COMPUTE(B)                                                              \
  {                                                                             \
    const ushort* ar = As[B] + aoff;                                            \
    const ushort* br = Bs[B] + boff;                                            \
    short8 bf[4];                                                               \
    bf[0] = *(const short8*)(br);                                               \
    bf[1] = *(const short8*)(br + 128);                                         \
    bf[2] = *(const short8*)(br + 256);                                         \
    bf[3] = *(const short8*)(br + 384);                                         \
    const short8 a0 = *(const short8*)(ar);                                     \
    const short8 a1 = *(const short8*)(ar + 128);                               \
    _Pragma("unroll")                                                           \
    for (int nb = 0; nb < 4; ++nb) {                                            \
      acc[0][nb] = __builtin_amdgcn_mfma_f32_16x16x32_bf16(a0, bf[nb], acc[0][nb], 0, 0, 0); \
      acc[1][nb] = __builtin_amdgcn_mfma_f32_16x16x32_bf16(a1, bf[nb], acc[1][nb], 0, 0, 0); \
    }                                                                           \
  }

  STAGE(0, 0)
  SYNCPT
  for (int k0 = 0; k0 < 512; k0 += 64) {
    STAGE(1, k0 + 32)
    COMPUTE(0)
    SYNCPT
    if (k0 + 64 < 512) { STAGE(0, k0 + 64) }
    COMPUTE(1)
    SYNCPT
  }
#undef STAGE
#undef SYNCPT
#undef COMPUTE

  // uint u of row holds chans (32*(u>>4)+(u&15), +16)
#pragma unroll
  for (int mb = 0; mb < 2; ++mb) {
    const int row0 = rowbase + wm * 32 + mb * 16 + l16 * 4;
#pragma unroll
    for (int r = 0; r < 4; ++r) {
      const int row = row0 + r;
      if (row < Nk) {
        uint* zp = Zp + ((size_t)kk * 2040 + row) * 128 + (colbase >> 1) + wn * 32 + l15;
        zp[0]  = pkh(acc[mb][0][r], acc[mb][1][r]);
        zp[16] = pkh(acc[mb][2][r], acc[mb][3][r]);
      }
    }
  }
}

// ---------- loss: 16 lanes/row = 2 neg-halves x 8 chan-lanes ----------
#if HAVE_SDOT8
// z signed int4 (zq4[0..3], nibble n of uint j = chan 32g+8j+n); pool biased
// nibbles un-biased on the fly: (q+8) ^ 8 = q in 4-bit two's complement.
#define PDOTP(P) ({                                                             \
    int d_ = 0;                                                                 \
    d_ = sdot8_(zq4[0], P.x ^ 0x88888888u, d_);                                 \
    d_ = sdot8_(zq4[1], P.y ^ 0x88888888u, d_);                                 \
    d_ = sdot8_(zq4[2], P.z ^ 0x88888888u, d_);                                 \
    d_ = sdot8_(zq4[3], P.w ^ 0x88888888u, d_);                                 \
    d_; })
#else
#define PDOTP(P) ({                                                             \
    int d0_ = 0, d1_ = 0;                                                       \
    uint e_, o_;                                                                \
    e_ = P.x & 0x0F0F0F0Fu; o_ = (P.x >> 4) & 0x0F0F0F0Fu;                      \
    d0_ = sdot4_(zq[0], e_, d0_); d1_ = sdot4_(zq[4], o_, d1_);                 \
    e_ = P.y & 0x0F0F0F0Fu; o_ = (P.y >> 4) & 0x0F0F0F0Fu;                      \
    d0_ = sdot4_(zq[1], e_, d0_); d1_ = sdot4_(zq[5], o_, d1_);                 \
    e_ = P.z & 0x0F0F0F0Fu; o_ = (P.z >> 4) & 0x0F0F0F0Fu;                      \
    d0_ = sdot4_(zq[2], e_, d0_); d1_ = sdot4_(zq[6], o_, d1_);                 \
    e_ = P.w & 0x0F0F0F0Fu; o_ = (P.w >> 4) & 0x0F0F0F0Fu;                      \
    d0_ = sdot4_(zq[3], e_, d0_); d1_ = sdot4_(zq[7], o_, d1_);                 \
    d0_ + d1_; })
#endif

#define DOTN(P) ({ int dd_ = PDOTP(P); qsum8i(dd_); })

#define LDB(P, IDX) P = *(const uint4*)(pbase + (size_t)(uint)(IDX) * 32);

// 3-round butterfly over the 8 chan-lanes: 8 per-lane partials -> one FULL
// integer dot per lane (each of the 8 lanes holds a distinct neg).
#define BFLY_ACC                                                                \
  {                                                                             \
    int x_, y_, u0_, u1_, u2_, u3_, r0_, r1_, full_;                            \
    x_ = sA ? pd1 : pd0; y_ = sA ? pd0 : pd1; u0_ = x_ + dpp_movi<0xB1>(y_);    \
    x_ = sA ? pd3 : pd2; y_ = sA ? pd2 : pd3; u1_ = x_ + dpp_movi<0xB1>(y_);    \
    x_ = sA ? pd5 : pd4; y_ = sA ? pd4 : pd5; u2_ = x_ + dpp_movi<0xB1>(y_);    \
    x_ = sA ? pd7 : pd6; y_ = sA ? pd6 : pd7; u3_ = x_ + dpp_movi<0xB1>(y_);    \
    x_ = sB ? u1_ : u0_; y_ = sB ? u0_ : u1_; r0_ = x_ + dpp_movi<0x4E>(y_);    \
    x_ = sB ? u3_ : u2_; y_ = sB ? u2_ : u3_; r1_ = x_ + dpp_movi<0x4E>(y_);    \
    x_ = sC ? r1_ : r0_; y_ = sC ? r0_ : r1_; full_ = x_ + dpp_movi<0x141>(y_); \
    s += exp2f(fmaf((float)full_, kG, c2m));                                    \
  }

__global__ __launch_bounds__(256) void loss_kernel(
    const uint* __restrict__ Zp, const uint* __restrict__ pool4,
    const int* __restrict__ neg_idx, float* __restrict__ acc) {
  const int kk = blockIdx.y;
  const int Tk = 255 - kk, Nk = 8 * Tk;
  if ((int)(blockIdx.x * 16) >= Nk) return;
  const int tid = threadIdx.x;
  const int n = blockIdx.x * 16 + (tid >> 4);
  const int l = tid & 15;
  const int h = l >> 3;   // neg half: negs [64h, 64h+64)
  const int g = l & 7;    // chan chunk: chans [32g, 32g+32)
  float row_loss = 0.f;
  if (n < Nk) {
    const uint* zr = Zp + ((size_t)kk * 2040 + n) * 128 + g * 16;
    uint zu[16];
#pragma unroll
    for (int i = 0; i < 4; ++i) *(uint4*)(zu + 4 * i) = *(const uint4*)(zr + 4 * i);
    float zf[32];
#pragma unroll
    for (int c = 0; c < 16; ++c) {
      const half2v hv = h2(zu[c]);
      zf[c] = (float)hv.x;
      zf[16 + c] = (float)hv.y;
    }
    float ss = 0.f;
#pragma unroll
    for (int i = 0; i < 32; ++i) ss = fmaf(zf[i], zf[i], ss);
    ss = dpp_add<0xB1>(ss); ss = dpp_add<0x4E>(ss); ss = dpp_add<0x141>(ss);

#if HAVE_SDOT8
    // z -> signed int4 at the pool's global step; nibble n of zq4[j] = chan 32g+8j+n
    const float s_z = rsqrtf(ss) * PQS;
    uint zq4[4];
#pragma unroll
    for (int j = 0; j < 4; ++j) {
      uint w = 0;
#pragma unroll
      for (int n2 = 0; n2 < 8; ++n2) {
        const int q = (int)rintf(fminf(fmaxf(zf[8 * j + n2] * s_z, -7.f), 7.f));
        w |= ((uint)(q & 15)) << (4 * n2);
      }
      zq4[j] = w;
    }
    int nq = 0;
#pragma unroll
    for (int j = 0; j < 4; ++j) nq = sdot8_(zq4[j], zq4[j], nq);
    nq = qsum8i(nq);
    const float kG = (INV_TEMP * L2E * PDELTA) * rsqrtf((float)nq);
    const float poseb = 0.f;
    const float c2m = -OFFE;
#else
    const float s127 = rsqrtf(ss) * 127.f;
    uint zq[8];
#pragma unroll
    for (int t = 0; t < 4; ++t) {
      const uint e0 = (uint)((int)rintf(zf[8 * t]     * s127) & 255);
      const uint e1 = (uint)((int)rintf(zf[8 * t + 2] * s127) & 255);
      const uint e2 = (uint)((int)rintf(zf[8 * t + 4] * s127) & 255);
      const uint e3 = (uint)((int)rintf(zf[8 * t + 6] * s127) & 255);
      zq[t] = e0 | (e1 << 8) | (e2 << 16) | (e3 << 24);
      const uint o0 = (uint)((int)rintf(zf[8 * t + 1] * s127) & 255);
      const uint o1 = (uint)((int)rintf(zf[8 * t + 3] * s127) & 255);
      const uint o2 = (uint)((int)rintf(zf[8 * t + 5] * s127) & 255);
      const uint o3 = (uint)((int)rintf(zf[8 * t + 7] * s127) & 255);
      zq[t + 4] = o0 | (o1 << 8) | (o2 << 16) | (o3 << 24);
    }
    int nq = 0, zs = 0;
#pragma unroll
    for (int t = 0; t < 8; ++t) {
      nq = sdot4_(zq[t], zq[t], nq);
      zs = sdot4_(zq[t], 0x01010101u, zs);
    }
    nq = qsum8i(nq);
    zs = qsum8i(zs);
    const float kG = (INV_TEMP * L2E * PDELTA) * rsqrtf((float)nq);
    const float poseb = -8.f * (float)zs * kG;  // bias term (biased pool)
    const float c2m = poseb - OFFE;
#endif

    const uint* pbase = pool4 + g * 4;
    const int bb = n / Tk, tt = n - bb * Tk;
    uint4 PP;
    LDB(PP, bb * 256 + tt + kk + 1)
    const float pose = fmaf((float)DOTN(PP), kG, poseb);

    // butterfly select masks (mirror-canonical index)
    const int mu = (g & 4) ? (7 - g) : g;
    const bool sA = (mu & 1) != 0;
    const bool sB = (mu & 2) != 0;
    const bool sC = (g & 4) != 0;

    // this half's 64 negs = 16 idx-quads; idx prefetched 2 iterations ahead,
    // pool gathers double-buffered 8-deep (A-D / E-H).
    const int4* ipq = (const int4*)(neg_idx + ((size_t)kk * 2040 + n) * 128 + h * 64);
    float s = 0.f;
    uint4 A, B, C, D, E, F, G, H;
    int4 q[16];
    q[0] = ipq[0]; q[1] = ipq[1]; q[2] = ipq[2]; q[3] = ipq[3];
    LDB(A, q[0].x) LDB(B, q[0].y) LDB(C, q[0].z) LDB(D, q[0].w)
#pragma unroll
    for (int j8 = 0; j8 < 8; ++j8) {
      LDB(E, q[2 * j8 + 1].x) LDB(F, q[2 * j8 + 1].y)
      LDB(G, q[2 * j8 + 1].z) LDB(H, q[2 * j8 + 1].w)
      if (j8 < 6) q[2 * j8 + 4] = ipq[2 * j8 + 4];   // idx prefetch
      const int pd0 = PDOTP(A), pd1 = PDOTP(B), pd2 = PDOTP(C), pd3 = PDOTP(D);
      if (j8 < 7) {
        LDB(A, q[2 * j8 + 2].x) LDB(B, q[2 * j8 + 2].y)
        LDB(C, q[2 * j8 + 2].z) LDB(D, q[2 * j8 + 2].w)
      }
      if (j8 < 6) q[2 * j8 + 5] = ipq[2 * j8 + 5];   // idx prefetch
      const int pd4 = PDOTP(E), pd5 = PDOTP(F), pd6 = PDOTP(G), pd7 = PDOTP(H);
      BFLY_ACC
    }
    // s holds distinct negs per lane; sum all 16 lanes of the row group
    const float sl = qsum16(s);
    const float ssum = sl + exp2f(pose - OFFE);
    row_loss = LOGIT_MAX + 0.69314718f * (__log2f(ssum) - pose);
  }
  __shared__ float bl[16];
  if (l == 0) bl[tid >> 4] = row_loss;
  __syncthreads();
  if (tid == 0) {
    float s2 = 0.f;
#pragma unroll
    for (int i = 0; i < 16; ++i) s2 += bl[i];
    atomicAdd(&acc[kk], s2);
  }
}

__global__ void finalize_kernel(const float* __restrict__ acc,
                                float* __restrict__ out) {
  if (threadIdx.x == 0) {
    float tot = 0.f;
#pragma unroll
    for (int kk = 0; kk < 12; ++kk) tot += acc[kk] / (8.0f * (255 - kk));
    out[0] = tot / 12.0f;
  }
}

extern "C" void kernel_launch(void* const* d_in, const int* in_sizes, int n_in,
                              void* d_out, int out_size, void* d_ws, size_t ws_size,
                              hipStream_t stream) {
  const float* ctx = (const float*)d_in[0];   // (8,256,512)
  const float* enc = (const float*)d_in[1];   // (8,256,256)
  const float* W   = (const float*)d_in[2];   // (12,256,512)
  const int*   neg = (const int*)d_in[3];     // (12,2040,128)
  float* out = (float*)d_out;

  char* ws = (char*)d_ws;
  uint*   pool4 = (uint*)(ws);                      // 262,144 B
  ushort* ctxb  = (ushort*)(ws + 262144);           // 2,097,152
  ushort* Wb    = (ushort*)(ws + 2359296);          // 3,145,728
  uint*   Zp    = (uint*)(ws + 5505024);            // 12,533,760
  float*  accb  = (float*)(ws + 18038784);          // 48 B

  prep_kernel<<<dim3(1408), dim3(256), 0, stream>>>(ctx, W, enc, ctxb, Wb, pool4, accb);
  zhat_gemm_kernel<<<dim3(2, 32, 12), dim3(256), 0, stream>>>(ctxb, Wb, Zp);
  loss_kernel<<<dim3(128, 12), dim3(256), 0, stream>>>(Zp, pool4, neg, accb);
  finalize_kernel<<<dim3(1), dim3(64), 0, stream>>>(accb, out);
}